// Round 3
// baseline (2723.041 us; speedup 1.0000x reference)
//
#include <hip/hip_runtime.h>

// M = 9 (lmax=2), NB = 32 channels, NRBF = 20, CUTOFF = 5, T = 2
#define CHUNK 16   // edges per 32-lane group in edge kernel

// ====================== compile-time CG table ======================
constexpr double CFACT[8] = {1.,1.,2.,6.,24.,120.,720.,5040.};

constexpr double csqrt(double x){
  if (x <= 0.0) return 0.0;
  double s = 1.0;
  while (x > 4.0)  { x *= 0.25; s *= 2.0; }
  while (x < 0.25) { x *= 4.0;  s *= 0.5; }
  double g = 1.0;
  for (int i=0;i<10;i++) g = 0.5*(g + x/g);
  return s*g;
}

constexpr double cg_complex(int j1,int m1,int j2,int m2,int j3,int m3){
  if (m3 != m1+m2 || j3 < (j1>j2?j1-j2:j2-j1) || j3 > j1+j2) return 0.0;
  double pref = csqrt((2.0*j3+1.0)*CFACT[j1+j2-j3]*CFACT[j1-j2+j3]*CFACT[-j1+j2+j3]/CFACT[j1+j2+j3+1]);
  pref *= csqrt(CFACT[j1+m1]*CFACT[j1-m1]*CFACT[j2+m2]*CFACT[j2-m2]*CFACT[j3+m3]*CFACT[j3-m3]);
  int kmin = 0;
  if (j2-j3-m1 > kmin) kmin = j2-j3-m1;
  if (j1+m2-j3 > kmin) kmin = j1+m2-j3;
  int kmax = j1+j2-j3;
  if (j1-m1 < kmax) kmax = j1-m1;
  if (j2+m2 < kmax) kmax = j2+m2;
  double s = 0.0;
  for (int k=kmin;k<=kmax;++k){
    double t = 1.0/(CFACT[k]*CFACT[j1+j2-j3-k]*CFACT[j1-m1-k]*CFACT[j2+m2-k]*CFACT[j3-j2+m1+k]*CFACT[j3-j1-m2+k]);
    s += (k&1)? -t : t;
  }
  return pref*s;
}

struct UR { int n; int mc[2]; double re[2]; double im[2]; };
constexpr UR u_row(int m){
  UR u{}; const double is2 = 0.70710678118654752440;
  if (m==0){ u.n=1; u.mc[0]=0; u.re[0]=1.0; u.im[0]=0.0; u.mc[1]=0; u.re[1]=0.0; u.im[1]=0.0; }
  else if (m>0){ u.n=2; u.mc[0]=m;  u.re[0]=((m&1)? -is2:is2); u.im[0]=0.0;
                        u.mc[1]=-m; u.re[1]=is2;               u.im[1]=0.0; }
  else { int mu=-m; u.n=2; u.mc[0]=m;  u.re[0]=0.0; u.im[0]=is2;
                           u.mc[1]=mu; u.re[1]=0.0; u.im[1]=((mu&1)? is2:-is2); }
  return u;
}

struct CGTab { float v[9][9][9]; };
constexpr CGTab build_cg(){
  CGTab g{};
  double cc[9][9][9] = {};
  for (int a=0;a<9;a++){
    int l1 = (a==0)?0:((a<4)?1:2); int m1 = a - (l1*l1+l1);
    for (int b=0;b<9;b++){
      int l2 = (b==0)?0:((b<4)?1:2); int m2 = b - (l2*l2+l2);
      int m3 = m1+m2;
      for (int l3=0;l3<=2;l3++){
        if (m3 < -l3 || m3 > l3) continue;
        cc[a][b][l3*l3+l3+m3] = cg_complex(l1,m1,l2,m2,l3,m3);
      }
    }
  }
  for (int l1=0;l1<=2;l1++) for (int l2=0;l2<=2;l2++) for (int l3=0;l3<=2;l3++){
    if (((l1+l2+l3)&1)==1) continue;
    int dl = (l1>l2)?(l1-l2):(l2-l1);
    if (l3 < dl || l3 > l1+l2) continue;
    for (int m1=-l1;m1<=l1;m1++) for (int m2=-l2;m2<=l2;m2++) for (int m3=-l3;m3<=l3;m3++){
      UR ua = u_row(m1), ub = u_row(m2), uc = u_row(m3);
      double acc = 0.0;
      for (int i=0;i<ua.n;i++) for (int j=0;j<ub.n;j++){
        double zr = ua.re[i]*ub.re[j] - ua.im[i]*ub.im[j];
        double zi = ua.re[i]*ub.im[j] + ua.im[i]*ub.re[j];
        for (int k=0;k<uc.n;k++){
          double rp = zr*uc.re[k] + zi*uc.im[k];   // Re[(za*zb)*conj(zc)]
          if (rp != 0.0)
            acc += rp * cc[l1*l1+l1+ua.mc[i]][l2*l2+l2+ub.mc[j]][l3*l3+l3+uc.mc[k]];
        }
      }
      g.v[l1*l1+l1+m1][l2*l2+l2+m2][l3*l3+l3+m3] = (float)acc;
    }
  }
  return g;
}
constexpr CGTab CGT = build_cg();

// ---------------- x init: x[:,0,:] = emb[Z], rest 0; also zero dx ----------
// float4-vectorized: 72 float4 per atom, first 8 come from emb
__global__ void init_x_kernel(const int* __restrict__ Z, const float* __restrict__ emb,
                              float4* __restrict__ x4, float4* __restrict__ dx4, int n_atoms){
  int i = blockIdx.x*blockDim.x + threadIdx.x;
  if (i >= n_atoms*72) return;
  int atom = i/72, rem = i - atom*72;
  float4 v = make_float4(0.f,0.f,0.f,0.f);
  if (rem < 8) v = reinterpret_cast<const float4*>(emb)[Z[atom]*8 + rem];
  x4[i] = v;
  dx4[i] = make_float4(0.f,0.f,0.f,0.f);
}

// ---------------- edge kernel ----------------
// 256 threads = 8 groups of 32 lanes; lane = channel n; each group does CHUNK
// consecutive edges. idx arrays preloaded per chunk (coalesced) + shuffled;
// xj gather software-pipelined one edge ahead. Wf weights live in LDS
// (shared by all groups) to keep VGPRs low. CG contraction is compile-time
// sparse immediates. Register accumulation over sorted-idx_i runs, atomicAdd
// flush on run change.
__global__ __launch_bounds__(256,6) void edge_kernel(
    const float* __restrict__ r_ij, const int* __restrict__ idx_i, const int* __restrict__ idx_j,
    const float* __restrict__ x, const float* __restrict__ Wf_t, const float* __restrict__ bf_t,
    float* __restrict__ dx, int n_edges)
{
  __shared__ __align__(16) float WfL[96*20];   // identity layout [row][20], rows 80B (16B-aligned)
  int tid = threadIdx.x;
  for (int i = tid; i < 96*20/4; i += 256)
    reinterpret_cast<float4*>(WfL)[i] = reinterpret_cast<const float4*>(Wf_t)[i];
  __syncthreads();

  int g = tid >> 5, lane = tid & 31;

  float bfl[3];
  #pragma unroll
  for (int l=0;l<3;l++) bfl[l] = bf_t[l*32+lane];

  const float STEP  = 5.0f/19.0f;
  const float ALPHA = -0.5f/(STEP*STEP);
  float myoff = (float)lane * STEP;   // lane >= 20: exp underflows to 0, harmless

  int base = (blockIdx.x*8 + g)*CHUNK;
  if (base >= n_edges) return;

  // preload this chunk's indices (coalesced; lanes 16..31 duplicate lanes 0..15)
  int pl = base + (lane & 15);
  if (pl > n_edges-1) pl = n_edges-1;
  int vj = idx_j[pl];
  int vi = idx_i[pl];

  const float4* w0 = reinterpret_cast<const float4*>(WfL + (0*32+lane)*20);
  const float4* w1 = reinterpret_cast<const float4*>(WfL + (1*32+lane)*20);
  const float4* w2 = reinterpret_cast<const float4*>(WfL + (2*32+lane)*20);

  float racc[9];
  #pragma unroll
  for (int c=0;c<9;c++) racc[c]=0.f;
  int cur_i = -1;

  // prefetch xj for edge 0
  float xjn[9];
  {
    int j0 = __shfl(vj, 0, 32);
    const float* xp = x + j0*288 + lane;
    #pragma unroll
    for (int b=0;b<9;b++) xjn[b] = xp[b*32];
  }

  for (int k=0;k<CHUNK;k++){
    int e = base + k;
    if (e >= n_edges) break;           // uniform within the group

    float xj[9];
    #pragma unroll
    for (int b=0;b<9;b++) xj[b] = xjn[b];

    // prefetch next edge's xj while computing this one
    if (k+1 < CHUNK){
      int jn = __shfl(vj, k+1, 32);
      const float* xp = x + jn*288 + lane;
      #pragma unroll
      for (int b=0;b<9;b++) xjn[b] = xp[b*32];
    }

    int ii = __shfl(vi, k, 32);

    float rx = r_ij[e*3+0], ry = r_ij[e*3+1], rz = r_ij[e*3+2];
    float d2 = fmaf(rx,rx,fmaf(ry,ry,rz*rz));
    float dd = sqrtf(d2);
    float inv = __fdividef(1.0f, dd);
    float X = rx*inv, Yv = ry*inv, Zv = rz*inv;
    const float c1 = 0.4886025119029199f, c2 = 1.0925484305920792f;
    float Y[9];
    Y[0]=0.28209479177387814f; Y[1]=c1*Yv; Y[2]=c1*Zv; Y[3]=c1*X;
    Y[4]=c2*X*Yv; Y[5]=c2*Yv*Zv; Y[6]=0.31539156525252005f*(3.f*Zv*Zv-1.f);
    Y[7]=c2*X*Zv; Y[8]=0.5462742152960396f*(X*X-Yv*Yv);

    // RBF: lane r computes its own basis value, broadcast via shuffle;
    // filter weights streamed from LDS (b128)
    float dtl = dd - myoff;
    float rbl = __expf(ALPHA*dtl*dtl);
    float wl0=bfl[0], wl1=bfl[1], wl2=bfl[2];
    #pragma unroll
    for (int q=0;q<5;q++){
      float4 a0 = w0[q], a1 = w1[q], a2 = w2[q];
      float rb0 = __shfl(rbl, 4*q+0, 32);
      float rb1 = __shfl(rbl, 4*q+1, 32);
      float rb2 = __shfl(rbl, 4*q+2, 32);
      float rb3 = __shfl(rbl, 4*q+3, 32);
      wl0 = fmaf(rb0,a0.x,wl0); wl0 = fmaf(rb1,a0.y,wl0); wl0 = fmaf(rb2,a0.z,wl0); wl0 = fmaf(rb3,a0.w,wl0);
      wl1 = fmaf(rb0,a1.x,wl1); wl1 = fmaf(rb1,a1.y,wl1); wl1 = fmaf(rb2,a1.z,wl1); wl1 = fmaf(rb3,a1.w,wl1);
      wl2 = fmaf(rb0,a2.x,wl2); wl2 = fmaf(rb1,a2.y,wl2); wl2 = fmaf(rb2,a2.z,wl2); wl2 = fmaf(rb3,a2.w,wl2);
    }
    float fc = (dd < 5.0f) ? 0.5f*(__cosf(dd*0.6283185307179586f)+1.0f) : 0.0f;
    wl0*=fc; wl1*=fc; wl2*=fc;

    if (ii != cur_i){
      if (cur_i >= 0){
        float* dp = dx + cur_i*288 + lane;
        #pragma unroll
        for (int c=0;c<9;c++){ atomicAdd(dp + c*32, racc[c]); racc[c]=0.f; }
      }
      cur_i = ii;
    }

    // yv[c] = sum_{a,b} Y[a] * CG[a][b][c] * xj[b]  (compile-time sparse)
    float yv[9];
    #pragma unroll
    for (int c=0;c<9;c++) yv[c]=0.f;
    #pragma unroll
    for (int a=0;a<9;a++){
      #pragma unroll
      for (int b=0;b<9;b++){
        bool any = false;
        #pragma unroll
        for (int c=0;c<9;c++) any = any | (CGT.v[a][b][c] != 0.f);
        if (any){
          float p = Y[a]*xj[b];
          #pragma unroll
          for (int c=0;c<9;c++){
            if (CGT.v[a][b][c] != 0.f) yv[c] = fmaf(CGT.v[a][b][c], p, yv[c]);
          }
        }
      }
    }
    racc[0] = fmaf(wl0, yv[0], racc[0]);
    #pragma unroll
    for (int c=1;c<4;c++) racc[c] = fmaf(wl1, yv[c], racc[c]);
    #pragma unroll
    for (int c=4;c<9;c++) racc[c] = fmaf(wl2, yv[c], racc[c]);
  }
  if (cur_i >= 0){
    float* dp = dx + cur_i*288 + lane;
    #pragma unroll
    for (int c=0;c<9;c++) atomicAdd(dp + c*32, racc[c]);
  }
}

// ---------------- atom kernel ----------------
// persistent-ish: grid-stride over atoms so the LDS weight staging is
// amortized over many atoms per block.
__global__ __launch_bounds__(256,4) void atom_kernel(
    float* __restrict__ x, float* __restrict__ dxg,
    const float* __restrict__ Wm1_t, const float* __restrict__ Wm2_t, const float* __restrict__ Wm3_t,
    const float* __restrict__ Wg_t, const float* __restrict__ bg_t, int n_atoms)
{
  __shared__ float W1T[1024], W2T[1024], W3T[1024];   // WT[n*32+k] = W[k*32+n]
  __shared__ float WgT[3072];                          // WgT[n*96+j] = Wg[j*32+n]
  __shared__ float bgs[96];
  __shared__ __align__(16) float tile[8][288];
  int tid = threadIdx.x;
  for (int i=tid;i<1024;i+=256){ int n=i>>5, kk=i&31; W1T[i]=Wm1_t[kk*32+n]; W2T[i]=Wm2_t[kk*32+n]; W3T[i]=Wm3_t[kk*32+n]; }
  for (int i=tid;i<3072;i+=256){ int n=i/96, jj=i-n*96; WgT[i]=Wg_t[jj*32+n]; }
  for (int i=tid;i<96;i+=256) bgs[i]=bg_t[i];
  __syncthreads();

  int g = tid>>5, k = tid&31;
  float* tg = &tile[g][0];
  const float4* t4 = reinterpret_cast<const float4*>(tg);

  float wr1[32], wr2[32], wr3[32];
  #pragma unroll
  for (int n=0;n<32;n++){ wr1[n]=W1T[n*32+k]; }

  for (int atom = blockIdx.x*8 + g; atom < n_atoms; atom += gridDim.x*8){
    float* dp = dxg + atom*288 + k;
    float v[9];
    #pragma unroll
    for (int c=0;c<9;c++){ v[c]=dp[c*32]; tg[c*32+k]=v[c]; dp[c*32]=0.f; }  // consume + re-zero

    // ddx = dx @ Wm1^T   (lane k = output channel)
    float u[9];
    #pragma unroll
    for (int c=0;c<9;c++){
      float s=0.f;
      #pragma unroll
      for (int q=0;q<8;q++){
        float4 tv = t4[c*8+q];
        s = fmaf(tv.x, wr1[4*q+0], s); s = fmaf(tv.y, wr1[4*q+1], s);
        s = fmaf(tv.z, wr1[4*q+2], s); s = fmaf(tv.w, wr1[4*q+3], s);
      }
      u[c]=s;
    }

    // w[c] = v[c] + sum_{a,b} CG[a][b][c] v[a] u[b]  (compile-time sparse)
    float w[9];
    #pragma unroll
    for (int c=0;c<9;c++) w[c]=v[c];
    #pragma unroll
    for (int a=0;a<9;a++){
      #pragma unroll
      for (int b=0;b<9;b++){
        bool any = false;
        #pragma unroll
        for (int c=0;c<9;c++) any = any | (CGT.v[a][b][c] != 0.f);
        if (any){
          float p = v[a]*u[b];
          #pragma unroll
          for (int c=0;c<9;c++){
            if (CGT.v[a][b][c] != 0.f) w[c] = fmaf(CGT.v[a][b][c], p, w[c]);
          }
        }
      }
    }

    // p = w @ Wm2^T
    #pragma unroll
    for (int c=0;c<9;c++) tg[c*32+k]=w[c];
    #pragma unroll
    for (int n=0;n<32;n++) wr2[n]=W2T[n*32+k];
    float p[9];
    #pragma unroll
    for (int c=0;c<9;c++){
      float s=0.f;
      #pragma unroll
      for (int q=0;q<8;q++){
        float4 tv = t4[c*8+q];
        s = fmaf(tv.x, wr2[4*q+0], s); s = fmaf(tv.y, wr2[4*q+1], s);
        s = fmaf(tv.z, wr2[4*q+2], s); s = fmaf(tv.w, wr2[4*q+3], s);
      }
      p[c]=s;
    }

    // gate from p[0,:]
    tg[k] = p[0];
    float s0=bgs[k], s1=bgs[32+k], s2=bgs[64+k];
    #pragma unroll
    for (int q=0;q<8;q++){
      float4 tv = t4[q];
      #pragma unroll
      for (int z=0;z<4;z++){
        float tvz = (z==0)?tv.x:((z==1)?tv.y:((z==2)?tv.z:tv.w));
        int n = 4*q+z;
        s0 = fmaf(tvz, WgT[n*96 + k],      s0);
        s1 = fmaf(tvz, WgT[n*96 + 32 + k], s1);
        s2 = fmaf(tvz, WgT[n*96 + 64 + k], s2);
      }
    }
    float h0 = 1.f/(1.f+__expf(-s0));
    float h1 = 1.f/(1.f+__expf(-s1));
    float h2 = 1.f/(1.f+__expf(-s2));

    float q9[9];
    q9[0]=p[0]*h0;
    #pragma unroll
    for (int c=1;c<4;c++) q9[c]=p[c]*h1;
    #pragma unroll
    for (int c=4;c<9;c++) q9[c]=p[c]*h2;

    // r = q @ Wm3^T ; x += r
    #pragma unroll
    for (int c=0;c<9;c++) tg[c*32+k]=q9[c];
    #pragma unroll
    for (int n=0;n<32;n++) wr3[n]=W3T[n*32+k];
    float* xo = x + atom*288 + k;
    #pragma unroll
    for (int c=0;c<9;c++){
      float s=0.f;
      #pragma unroll
      for (int q=0;q<8;q++){
        float4 tv = t4[c*8+q];
        s = fmaf(tv.x, wr3[4*q+0], s); s = fmaf(tv.y, wr3[4*q+1], s);
        s = fmaf(tv.z, wr3[4*q+2], s); s = fmaf(tv.w, wr3[4*q+3], s);
      }
      xo[c*32] += s;
    }
  }
}

// ---------------- launch ----------------
extern "C" void kernel_launch(void* const* d_in, const int* in_sizes, int n_in,
                              void* d_out, int out_size, void* d_ws, size_t ws_size,
                              hipStream_t stream)
{
  const int*   Z    = (const int*)d_in[0];
  const float* r_ij = (const float*)d_in[1];
  const int*   idxi = (const int*)d_in[2];
  const int*   idxj = (const int*)d_in[3];
  const float* emb  = (const float*)d_in[4];
  const float* Wf   = (const float*)d_in[5];
  const float* bf   = (const float*)d_in[6];
  const float* Wm1  = (const float*)d_in[7];
  const float* Wm2  = (const float*)d_in[8];
  const float* Wm3  = (const float*)d_in[9];
  const float* Wg   = (const float*)d_in[10];
  const float* bg   = (const float*)d_in[11];
  int n_atoms = in_sizes[0];
  int n_edges = in_sizes[1]/3;

  float* x  = (float*)d_out;
  float* dx = (float*)d_ws;

  init_x_kernel<<<(n_atoms*72+255)/256,256,0,stream>>>(Z, emb, (float4*)x, (float4*)dx, n_atoms);

  int ablocks = (n_atoms + 7)/8; if (ablocks > 640) ablocks = 640;
  for (int t=0;t<2;t++){
    int eblocks = (n_edges + 8*CHUNK - 1)/(8*CHUNK);
    edge_kernel<<<eblocks,256,0,stream>>>(r_ij, idxi, idxj, x,
                                          Wf + t*96*20, bf + t*96, dx, n_edges);
    atom_kernel<<<ablocks,256,0,stream>>>(x, dx,
                                          Wm1 + t*1024, Wm2 + t*1024, Wm3 + t*1024,
                                          Wg + t*96*32, bg + t*96, n_atoms);
  }
}

// Round 4
// 433.226 us; speedup vs baseline: 6.2855x; 6.2855x over previous
//
#include <hip/hip_runtime.h>

// M = 9 (lmax=2), NB = 32 channels, NRBF = 20, CUTOFF = 5, T = 2
#define CHUNK 16   // edges per 32-lane group in edge kernel

// ====================== compile-time CG table ======================
constexpr double CFACT[8] = {1.,1.,2.,6.,24.,120.,720.,5040.};

constexpr double csqrt(double x){
  if (x <= 0.0) return 0.0;
  double s = 1.0;
  while (x > 4.0)  { x *= 0.25; s *= 2.0; }
  while (x < 0.25) { x *= 4.0;  s *= 0.5; }
  double g = 1.0;
  for (int i=0;i<10;i++) g = 0.5*(g + x/g);
  return s*g;
}

constexpr double cg_complex(int j1,int m1,int j2,int m2,int j3,int m3){
  if (m3 != m1+m2 || j3 < (j1>j2?j1-j2:j2-j1) || j3 > j1+j2) return 0.0;
  double pref = csqrt((2.0*j3+1.0)*CFACT[j1+j2-j3]*CFACT[j1-j2+j3]*CFACT[-j1+j2+j3]/CFACT[j1+j2+j3+1]);
  pref *= csqrt(CFACT[j1+m1]*CFACT[j1-m1]*CFACT[j2+m2]*CFACT[j2-m2]*CFACT[j3+m3]*CFACT[j3-m3]);
  int kmin = 0;
  if (j2-j3-m1 > kmin) kmin = j2-j3-m1;
  if (j1+m2-j3 > kmin) kmin = j1+m2-j3;
  int kmax = j1+j2-j3;
  if (j1-m1 < kmax) kmax = j1-m1;
  if (j2+m2 < kmax) kmax = j2+m2;
  double s = 0.0;
  for (int k=kmin;k<=kmax;++k){
    double t = 1.0/(CFACT[k]*CFACT[j1+j2-j3-k]*CFACT[j1-m1-k]*CFACT[j2+m2-k]*CFACT[j3-j2+m1+k]*CFACT[j3-j1-m2+k]);
    s += (k&1)? -t : t;
  }
  return pref*s;
}

struct UR { int n; int mc[2]; double re[2]; double im[2]; };
constexpr UR u_row(int m){
  UR u{}; const double is2 = 0.70710678118654752440;
  if (m==0){ u.n=1; u.mc[0]=0; u.re[0]=1.0; u.im[0]=0.0; u.mc[1]=0; u.re[1]=0.0; u.im[1]=0.0; }
  else if (m>0){ u.n=2; u.mc[0]=m;  u.re[0]=((m&1)? -is2:is2); u.im[0]=0.0;
                        u.mc[1]=-m; u.re[1]=is2;               u.im[1]=0.0; }
  else { int mu=-m; u.n=2; u.mc[0]=m;  u.re[0]=0.0; u.im[0]=is2;
                           u.mc[1]=mu; u.re[1]=0.0; u.im[1]=((mu&1)? is2:-is2); }
  return u;
}

struct CGTab { float v[9][9][9]; };
constexpr CGTab build_cg(){
  CGTab g{};
  double cc[9][9][9] = {};
  for (int a=0;a<9;a++){
    int l1 = (a==0)?0:((a<4)?1:2); int m1 = a - (l1*l1+l1);
    for (int b=0;b<9;b++){
      int l2 = (b==0)?0:((b<4)?1:2); int m2 = b - (l2*l2+l2);
      int m3 = m1+m2;
      for (int l3=0;l3<=2;l3++){
        if (m3 < -l3 || m3 > l3) continue;
        cc[a][b][l3*l3+l3+m3] = cg_complex(l1,m1,l2,m2,l3,m3);
      }
    }
  }
  for (int l1=0;l1<=2;l1++) for (int l2=0;l2<=2;l2++) for (int l3=0;l3<=2;l3++){
    if (((l1+l2+l3)&1)==1) continue;
    int dl = (l1>l2)?(l1-l2):(l2-l1);
    if (l3 < dl || l3 > l1+l2) continue;
    for (int m1=-l1;m1<=l1;m1++) for (int m2=-l2;m2<=l2;m2++) for (int m3=-l3;m3<=l3;m3++){
      UR ua = u_row(m1), ub = u_row(m2), uc = u_row(m3);
      double acc = 0.0;
      for (int i=0;i<ua.n;i++) for (int j=0;j<ub.n;j++){
        double zr = ua.re[i]*ub.re[j] - ua.im[i]*ub.im[j];
        double zi = ua.re[i]*ub.im[j] + ua.im[i]*ub.re[j];
        for (int k=0;k<uc.n;k++){
          double rp = zr*uc.re[k] + zi*uc.im[k];   // Re[(za*zb)*conj(zc)]
          if (rp != 0.0)
            acc += rp * cc[l1*l1+l1+ua.mc[i]][l2*l2+l2+ub.mc[j]][l3*l3+l3+uc.mc[k]];
        }
      }
      g.v[l1*l1+l1+m1][l2*l2+l2+m2][l3*l3+l3+m3] = (float)acc;
    }
  }
  return g;
}
constexpr CGTab CGT = build_cg();

// ---------------- x init: x[:,0,:] = emb[Z], rest 0; also zero dx ----------
__global__ void init_x_kernel(const int* __restrict__ Z, const float* __restrict__ emb,
                              float4* __restrict__ x4, float4* __restrict__ dx4, int n_atoms){
  int i = blockIdx.x*blockDim.x + threadIdx.x;
  if (i >= n_atoms*72) return;
  int atom = i/72, rem = i - atom*72;
  float4 v = make_float4(0.f,0.f,0.f,0.f);
  if (rem < 8) v = reinterpret_cast<const float4*>(emb)[Z[atom]*8 + rem];
  x4[i] = v;
  dx4[i] = make_float4(0.f,0.f,0.f,0.f);
}

// ---------------- edge kernel ----------------
// 256 threads = 8 groups of 32 lanes; lane = channel n; each group does CHUNK
// consecutive edges. Chunk indices + r_ij preloaded coalesced and distributed
// by shuffle; xj gather software-pipelined one edge ahead. Wf filter weights
// in per-lane registers (60 VGPRs — deliberate; forcing them out spills,
// see R3 post-mortem). CG contraction = compile-time sparse immediates.
// Register accumulation over sorted-idx_i runs, atomicAdd flush on change.
__global__ __launch_bounds__(256) void edge_kernel(
    const float* __restrict__ r_ij, const int* __restrict__ idx_i, const int* __restrict__ idx_j,
    const float* __restrict__ x, const float* __restrict__ Wf_t, const float* __restrict__ bf_t,
    float* __restrict__ dx, int n_edges)
{
  int tid = threadIdx.x;
  int g = tid >> 5, lane = tid & 31;

  int base = (blockIdx.x*8 + g)*CHUNK;
  if (base >= n_edges) return;

  // ---- chunk preloads (coalesced) ----
  // lanes 0..15: idx_i[base+lane]; lanes 16..31: idx_j[base+lane-16]
  int pidx;
  {
    int e0 = base + (lane & 15);
    if (e0 > n_edges-1) e0 = n_edges-1;
    pidx = (lane < 16) ? idx_i[e0] : idx_j[e0];
  }
  // 48 r_ij floats for the chunk
  float rv0, rv1;
  {
    long long rmax = (long long)n_edges*3 - 1;
    long long a0 = (long long)base*3 + lane;       if (a0 > rmax) a0 = rmax;
    long long a1 = (long long)base*3 + 32 + lane;  if (a1 > rmax) a1 = rmax;
    rv0 = r_ij[a0];
    rv1 = r_ij[a1];
  }

  // per-lane filter weights in registers (reused across all edges)
  float wfr[3][20]; float bfl[3];
  #pragma unroll
  for (int l=0;l<3;l++){
    const float* rp = Wf_t + (l*32+lane)*20;   // 80B rows -> 16B aligned
    #pragma unroll
    for (int q=0;q<5;q++){
      float4 v4 = *reinterpret_cast<const float4*>(rp + q*4);
      wfr[l][q*4+0]=v4.x; wfr[l][q*4+1]=v4.y; wfr[l][q*4+2]=v4.z; wfr[l][q*4+3]=v4.w;
    }
    bfl[l] = bf_t[l*32+lane];
  }

  const float STEP  = 5.0f/19.0f;
  const float ALPHA = -0.5f/(STEP*STEP);
  float myoff = (float)lane * STEP;   // lane >= 20: exp underflows to 0, harmless

  float racc[9];
  #pragma unroll
  for (int c=0;c<9;c++) racc[c]=0.f;
  int cur_i = -1;

  // prefetch xj for edge 0
  float xjn[9];
  {
    int j0 = __shfl(pidx, 16, 32);
    const float* xp = x + j0*288 + lane;
    #pragma unroll
    for (int b=0;b<9;b++) xjn[b] = xp[b*32];
  }

  #pragma unroll
  for (int k=0;k<CHUNK;k++){
    int e = base + k;
    if (e >= n_edges) break;           // uniform within the group

    float xj[9];
    #pragma unroll
    for (int b=0;b<9;b++) xj[b] = xjn[b];

    // prefetch next edge's xj while computing this one
    if (k+1 < CHUNK){
      int jn = __shfl(pidx, 16+k+1, 32);
      const float* xp = x + jn*288 + lane;
      #pragma unroll
      for (int b=0;b<9;b++) xjn[b] = xp[b*32];
    }

    int ii = __shfl(pidx, k, 32);

    // r_ij components from the preloaded chunk (compile-time lane indices)
    float rx = (3*k+0 < 32) ? __shfl(rv0, 3*k+0, 32) : __shfl(rv1, 3*k+0-32, 32);
    float ry = (3*k+1 < 32) ? __shfl(rv0, 3*k+1, 32) : __shfl(rv1, 3*k+1-32, 32);
    float rz = (3*k+2 < 32) ? __shfl(rv0, 3*k+2, 32) : __shfl(rv1, 3*k+2-32, 32);

    float d2 = fmaf(rx,rx,fmaf(ry,ry,rz*rz));
    float dd = sqrtf(d2);
    float inv = __fdividef(1.0f, dd);
    float X = rx*inv, Yv = ry*inv, Zv = rz*inv;
    const float c1 = 0.4886025119029199f, c2 = 1.0925484305920792f;
    float Y[9];
    Y[0]=0.28209479177387814f; Y[1]=c1*Yv; Y[2]=c1*Zv; Y[3]=c1*X;
    Y[4]=c2*X*Yv; Y[5]=c2*Yv*Zv; Y[6]=0.31539156525252005f*(3.f*Zv*Zv-1.f);
    Y[7]=c2*X*Zv; Y[8]=0.5462742152960396f*(X*X-Yv*Yv);

    // RBF: lane r computes its own basis value, broadcast via shuffle
    float dtl = dd - myoff;
    float rbl = __expf(ALPHA*dtl*dtl);
    float wl0=bfl[0], wl1=bfl[1], wl2=bfl[2];
    #pragma unroll
    for (int r=0;r<20;r++){
      float rb = __shfl(rbl, r, 32);
      wl0 = fmaf(rb, wfr[0][r], wl0);
      wl1 = fmaf(rb, wfr[1][r], wl1);
      wl2 = fmaf(rb, wfr[2][r], wl2);
    }
    float fc = (dd < 5.0f) ? 0.5f*(__cosf(dd*0.6283185307179586f)+1.0f) : 0.0f;
    wl0*=fc; wl1*=fc; wl2*=fc;

    if (ii != cur_i){
      if (cur_i >= 0){
        float* dp = dx + cur_i*288 + lane;
        #pragma unroll
        for (int c=0;c<9;c++){ atomicAdd(dp + c*32, racc[c]); racc[c]=0.f; }
      }
      cur_i = ii;
    }

    // yv[c] = sum_{a,b} Y[a] * CG[a][b][c] * xj[b]  (compile-time sparse)
    float yv[9];
    #pragma unroll
    for (int c=0;c<9;c++) yv[c]=0.f;
    #pragma unroll
    for (int a=0;a<9;a++){
      #pragma unroll
      for (int b=0;b<9;b++){
        bool any = false;
        #pragma unroll
        for (int c=0;c<9;c++) any = any | (CGT.v[a][b][c] != 0.f);
        if (any){
          float p = Y[a]*xj[b];
          #pragma unroll
          for (int c=0;c<9;c++){
            if (CGT.v[a][b][c] != 0.f) yv[c] = fmaf(CGT.v[a][b][c], p, yv[c]);
          }
        }
      }
    }
    racc[0] = fmaf(wl0, yv[0], racc[0]);
    #pragma unroll
    for (int c=1;c<4;c++) racc[c] = fmaf(wl1, yv[c], racc[c]);
    #pragma unroll
    for (int c=4;c<9;c++) racc[c] = fmaf(wl2, yv[c], racc[c]);
  }
  if (cur_i >= 0){
    float* dp = dx + cur_i*288 + lane;
    #pragma unroll
    for (int c=0;c<9;c++) atomicAdd(dp + c*32, racc[c]);
  }
}

// ---------------- atom kernel ----------------
// grid-stride so the LDS weight staging is amortized over many atoms/block.
__global__ __launch_bounds__(256,4) void atom_kernel(
    float* __restrict__ x, float* __restrict__ dxg,
    const float* __restrict__ Wm1_t, const float* __restrict__ Wm2_t, const float* __restrict__ Wm3_t,
    const float* __restrict__ Wg_t, const float* __restrict__ bg_t, int n_atoms)
{
  __shared__ float W1T[1024], W2T[1024], W3T[1024];   // WT[n*32+k] = W[k*32+n]
  __shared__ float WgT[3072];                          // WgT[n*96+j] = Wg[j*32+n]
  __shared__ float bgs[96];
  __shared__ __align__(16) float tile[8][288];
  int tid = threadIdx.x;
  for (int i=tid;i<1024;i+=256){ int n=i>>5, kk=i&31; W1T[i]=Wm1_t[kk*32+n]; W2T[i]=Wm2_t[kk*32+n]; W3T[i]=Wm3_t[kk*32+n]; }
  for (int i=tid;i<3072;i+=256){ int n=i/96, jj=i-n*96; WgT[i]=Wg_t[jj*32+n]; }
  for (int i=tid;i<96;i+=256) bgs[i]=bg_t[i];
  __syncthreads();

  int g = tid>>5, k = tid&31;
  float* tg = &tile[g][0];
  const float4* t4 = reinterpret_cast<const float4*>(tg);

  float wr1[32], wr2[32], wr3[32];
  #pragma unroll
  for (int n=0;n<32;n++){ wr1[n]=W1T[n*32+k]; }

  for (int atom = blockIdx.x*8 + g; atom < n_atoms; atom += gridDim.x*8){
    float* dp = dxg + atom*288 + k;
    float v[9];
    #pragma unroll
    for (int c=0;c<9;c++){ v[c]=dp[c*32]; tg[c*32+k]=v[c]; dp[c*32]=0.f; }  // consume + re-zero

    // ddx = dx @ Wm1^T   (lane k = output channel)
    float u[9];
    #pragma unroll
    for (int c=0;c<9;c++){
      float s=0.f;
      #pragma unroll
      for (int q=0;q<8;q++){
        float4 tv = t4[c*8+q];
        s = fmaf(tv.x, wr1[4*q+0], s); s = fmaf(tv.y, wr1[4*q+1], s);
        s = fmaf(tv.z, wr1[4*q+2], s); s = fmaf(tv.w, wr1[4*q+3], s);
      }
      u[c]=s;
    }

    // w[c] = v[c] + sum_{a,b} CG[a][b][c] v[a] u[b]  (compile-time sparse)
    float w[9];
    #pragma unroll
    for (int c=0;c<9;c++) w[c]=v[c];
    #pragma unroll
    for (int a=0;a<9;a++){
      #pragma unroll
      for (int b=0;b<9;b++){
        bool any = false;
        #pragma unroll
        for (int c=0;c<9;c++) any = any | (CGT.v[a][b][c] != 0.f);
        if (any){
          float p = v[a]*u[b];
          #pragma unroll
          for (int c=0;c<9;c++){
            if (CGT.v[a][b][c] != 0.f) w[c] = fmaf(CGT.v[a][b][c], p, w[c]);
          }
        }
      }
    }

    // p = w @ Wm2^T
    #pragma unroll
    for (int c=0;c<9;c++) tg[c*32+k]=w[c];
    #pragma unroll
    for (int n=0;n<32;n++) wr2[n]=W2T[n*32+k];
    float p[9];
    #pragma unroll
    for (int c=0;c<9;c++){
      float s=0.f;
      #pragma unroll
      for (int q=0;q<8;q++){
        float4 tv = t4[c*8+q];
        s = fmaf(tv.x, wr2[4*q+0], s); s = fmaf(tv.y, wr2[4*q+1], s);
        s = fmaf(tv.z, wr2[4*q+2], s); s = fmaf(tv.w, wr2[4*q+3], s);
      }
      p[c]=s;
    }

    // gate from p[0,:]
    tg[k] = p[0];
    float s0=bgs[k], s1=bgs[32+k], s2=bgs[64+k];
    #pragma unroll
    for (int q=0;q<8;q++){
      float4 tv = t4[q];
      #pragma unroll
      for (int z=0;z<4;z++){
        float tvz = (z==0)?tv.x:((z==1)?tv.y:((z==2)?tv.z:tv.w));
        int n = 4*q+z;
        s0 = fmaf(tvz, WgT[n*96 + k],      s0);
        s1 = fmaf(tvz, WgT[n*96 + 32 + k], s1);
        s2 = fmaf(tvz, WgT[n*96 + 64 + k], s2);
      }
    }
    float h0 = 1.f/(1.f+__expf(-s0));
    float h1 = 1.f/(1.f+__expf(-s1));
    float h2 = 1.f/(1.f+__expf(-s2));

    float q9[9];
    q9[0]=p[0]*h0;
    #pragma unroll
    for (int c=1;c<4;c++) q9[c]=p[c]*h1;
    #pragma unroll
    for (int c=4;c<9;c++) q9[c]=p[c]*h2;

    // r = q @ Wm3^T ; x += r
    #pragma unroll
    for (int c=0;c<9;c++) tg[c*32+k]=q9[c];
    #pragma unroll
    for (int n=0;n<32;n++) wr3[n]=W3T[n*32+k];
    float* xo = x + atom*288 + k;
    #pragma unroll
    for (int c=0;c<9;c++){
      float s=0.f;
      #pragma unroll
      for (int q=0;q<8;q++){
        float4 tv = t4[c*8+q];
        s = fmaf(tv.x, wr3[4*q+0], s); s = fmaf(tv.y, wr3[4*q+1], s);
        s = fmaf(tv.z, wr3[4*q+2], s); s = fmaf(tv.w, wr3[4*q+3], s);
      }
      xo[c*32] += s;
    }
  }
}

// ---------------- launch ----------------
extern "C" void kernel_launch(void* const* d_in, const int* in_sizes, int n_in,
                              void* d_out, int out_size, void* d_ws, size_t ws_size,
                              hipStream_t stream)
{
  const int*   Z    = (const int*)d_in[0];
  const float* r_ij = (const float*)d_in[1];
  const int*   idxi = (const int*)d_in[2];
  const int*   idxj = (const int*)d_in[3];
  const float* emb  = (const float*)d_in[4];
  const float* Wf   = (const float*)d_in[5];
  const float* bf   = (const float*)d_in[6];
  const float* Wm1  = (const float*)d_in[7];
  const float* Wm2  = (const float*)d_in[8];
  const float* Wm3  = (const float*)d_in[9];
  const float* Wg   = (const float*)d_in[10];
  const float* bg   = (const float*)d_in[11];
  int n_atoms = in_sizes[0];
  int n_edges = in_sizes[1]/3;

  float* x  = (float*)d_out;
  float* dx = (float*)d_ws;

  init_x_kernel<<<(n_atoms*72+255)/256,256,0,stream>>>(Z, emb, (float4*)x, (float4*)dx, n_atoms);

  int ablocks = (n_atoms + 7)/8; if (ablocks > 640) ablocks = 640;
  for (int t=0;t<2;t++){
    int eblocks = (n_edges + 8*CHUNK - 1)/(8*CHUNK);
    edge_kernel<<<eblocks,256,0,stream>>>(r_ij, idxi, idxj, x,
                                          Wf + t*96*20, bf + t*96, dx, n_edges);
    atom_kernel<<<ablocks,256,0,stream>>>(x, dx,
                                          Wm1 + t*1024, Wm2 + t*1024, Wm3 + t*1024,
                                          Wg + t*96*32, bg + t*96, n_atoms);
  }
}

// Round 5
// 414.759 us; speedup vs baseline: 6.5654x; 1.0445x over previous
//
#include <hip/hip_runtime.h>

// M = 9 (lmax=2), NB = 32 channels, NRBF = 20, CUTOFF = 5, T = 2
#define CHUNK 16   // edges per 32-lane group in edge kernel

// ====================== compile-time CG table ======================
constexpr double CFACT[8] = {1.,1.,2.,6.,24.,120.,720.,5040.};

constexpr double csqrt(double x){
  if (x <= 0.0) return 0.0;
  double s = 1.0;
  while (x > 4.0)  { x *= 0.25; s *= 2.0; }
  while (x < 0.25) { x *= 4.0;  s *= 0.5; }
  double g = 1.0;
  for (int i=0;i<10;i++) g = 0.5*(g + x/g);
  return s*g;
}

constexpr double cg_complex(int j1,int m1,int j2,int m2,int j3,int m3){
  if (m3 != m1+m2 || j3 < (j1>j2?j1-j2:j2-j1) || j3 > j1+j2) return 0.0;
  double pref = csqrt((2.0*j3+1.0)*CFACT[j1+j2-j3]*CFACT[j1-j2+j3]*CFACT[-j1+j2+j3]/CFACT[j1+j2+j3+1]);
  pref *= csqrt(CFACT[j1+m1]*CFACT[j1-m1]*CFACT[j2+m2]*CFACT[j2-m2]*CFACT[j3+m3]*CFACT[j3-m3]);
  int kmin = 0;
  if (j2-j3-m1 > kmin) kmin = j2-j3-m1;
  if (j1+m2-j3 > kmin) kmin = j1+m2-j3;
  int kmax = j1+j2-j3;
  if (j1-m1 < kmax) kmax = j1-m1;
  if (j2+m2 < kmax) kmax = j2+m2;
  double s = 0.0;
  for (int k=kmin;k<=kmax;++k){
    double t = 1.0/(CFACT[k]*CFACT[j1+j2-j3-k]*CFACT[j1-m1-k]*CFACT[j2+m2-k]*CFACT[j3-j2+m1+k]*CFACT[j3-j1-m2+k]);
    s += (k&1)? -t : t;
  }
  return pref*s;
}

struct UR { int n; int mc[2]; double re[2]; double im[2]; };
constexpr UR u_row(int m){
  UR u{}; const double is2 = 0.70710678118654752440;
  if (m==0){ u.n=1; u.mc[0]=0; u.re[0]=1.0; u.im[0]=0.0; u.mc[1]=0; u.re[1]=0.0; u.im[1]=0.0; }
  else if (m>0){ u.n=2; u.mc[0]=m;  u.re[0]=((m&1)? -is2:is2); u.im[0]=0.0;
                        u.mc[1]=-m; u.re[1]=is2;               u.im[1]=0.0; }
  else { int mu=-m; u.n=2; u.mc[0]=m;  u.re[0]=0.0; u.im[0]=is2;
                           u.mc[1]=mu; u.re[1]=0.0; u.im[1]=((mu&1)? is2:-is2); }
  return u;
}

struct CGTab { float v[9][9][9]; };
constexpr CGTab build_cg(){
  CGTab g{};
  double cc[9][9][9] = {};
  for (int a=0;a<9;a++){
    int l1 = (a==0)?0:((a<4)?1:2); int m1 = a - (l1*l1+l1);
    for (int b=0;b<9;b++){
      int l2 = (b==0)?0:((b<4)?1:2); int m2 = b - (l2*l2+l2);
      int m3 = m1+m2;
      for (int l3=0;l3<=2;l3++){
        if (m3 < -l3 || m3 > l3) continue;
        cc[a][b][l3*l3+l3+m3] = cg_complex(l1,m1,l2,m2,l3,m3);
      }
    }
  }
  for (int l1=0;l1<=2;l1++) for (int l2=0;l2<=2;l2++) for (int l3=0;l3<=2;l3++){
    if (((l1+l2+l3)&1)==1) continue;
    int dl = (l1>l2)?(l1-l2):(l2-l1);
    if (l3 < dl || l3 > l1+l2) continue;
    for (int m1=-l1;m1<=l1;m1++) for (int m2=-l2;m2<=l2;m2++) for (int m3=-l3;m3<=l3;m3++){
      UR ua = u_row(m1), ub = u_row(m2), uc = u_row(m3);
      double acc = 0.0;
      for (int i=0;i<ua.n;i++) for (int j=0;j<ub.n;j++){
        double zr = ua.re[i]*ub.re[j] - ua.im[i]*ub.im[j];
        double zi = ua.re[i]*ub.im[j] + ua.im[i]*ub.re[j];
        for (int k=0;k<uc.n;k++){
          double rp = zr*uc.re[k] + zi*uc.im[k];   // Re[(za*zb)*conj(zc)]
          if (rp != 0.0)
            acc += rp * cc[l1*l1+l1+ua.mc[i]][l2*l2+l2+ub.mc[j]][l3*l3+l3+uc.mc[k]];
        }
      }
      g.v[l1*l1+l1+m1][l2*l2+l2+m2][l3*l3+l3+m3] = (float)acc;
    }
  }
  return g;
}
constexpr CGTab CGT = build_cg();

// ---------------- x init: x[:,0,:] = emb[Z], rest 0; also zero dx ----------
__global__ void init_x_kernel(const int* __restrict__ Z, const float* __restrict__ emb,
                              float4* __restrict__ x4, float4* __restrict__ dx4, int n_atoms){
  int i = blockIdx.x*blockDim.x + threadIdx.x;
  if (i >= n_atoms*72) return;
  int atom = i/72, rem = i - atom*72;
  float4 v = make_float4(0.f,0.f,0.f,0.f);
  if (rem < 8) v = reinterpret_cast<const float4*>(emb)[Z[atom]*8 + rem];
  x4[i] = v;
  dx4[i] = make_float4(0.f,0.f,0.f,0.f);
}

// ---------------- edge kernel ----------------
// 256 threads = 8 groups of 32 lanes; lane = channel n; each group does CHUNK
// consecutive edges. Chunk indices + r_ij preloaded coalesced and distributed
// by shuffle; xj gather software-pipelined one edge ahead. Wf filter weights
// in per-lane registers (60 VGPRs — deliberate; forcing them to LDS spills,
// see R3 post-mortem). CG contraction = compile-time sparse immediates.
// FIRST=true (t=0): x[:,1:,:]==0 and CG[a][0][c]==delta_ac exactly, so
// yij[c] = Y[c]*x[j,0,:] — one coalesced gather, no CG contraction.
template<bool FIRST>
__global__ __launch_bounds__(256) void edge_kernel(
    const float* __restrict__ r_ij, const int* __restrict__ idx_i, const int* __restrict__ idx_j,
    const float* __restrict__ x, const float* __restrict__ Wf_t, const float* __restrict__ bf_t,
    float* __restrict__ dx, int n_edges)
{
  int tid = threadIdx.x;
  int g = tid >> 5, lane = tid & 31;

  int base = (blockIdx.x*8 + g)*CHUNK;
  if (base >= n_edges) return;

  // ---- chunk preloads (coalesced) ----
  // lanes 0..15: idx_i[base+lane]; lanes 16..31: idx_j[base+lane-16]
  int pidx;
  {
    int e0 = base + (lane & 15);
    if (e0 > n_edges-1) e0 = n_edges-1;
    pidx = (lane < 16) ? idx_i[e0] : idx_j[e0];
  }
  // 48 r_ij floats for the chunk
  float rv0, rv1;
  {
    long long rmax = (long long)n_edges*3 - 1;
    long long a0 = (long long)base*3 + lane;       if (a0 > rmax) a0 = rmax;
    long long a1 = (long long)base*3 + 32 + lane;  if (a1 > rmax) a1 = rmax;
    rv0 = r_ij[a0];
    rv1 = r_ij[a1];
  }

  // per-lane filter weights in registers (reused across all edges)
  float wfr[3][20]; float bfl[3];
  #pragma unroll
  for (int l=0;l<3;l++){
    const float* rp = Wf_t + (l*32+lane)*20;   // 80B rows -> 16B aligned
    #pragma unroll
    for (int q=0;q<5;q++){
      float4 v4 = *reinterpret_cast<const float4*>(rp + q*4);
      wfr[l][q*4+0]=v4.x; wfr[l][q*4+1]=v4.y; wfr[l][q*4+2]=v4.z; wfr[l][q*4+3]=v4.w;
    }
    bfl[l] = bf_t[l*32+lane];
  }

  const float STEP  = 5.0f/19.0f;
  const float ALPHA = -0.5f/(STEP*STEP);
  float myoff = (float)lane * STEP;   // lane >= 20: exp underflows to 0, harmless

  float racc[9];
  #pragma unroll
  for (int c=0;c<9;c++) racc[c]=0.f;
  int cur_i = -1;

  // prefetch xj for edge 0
  float xjn[9];
  float xjn0;
  {
    int j0 = __shfl(pidx, 16, 32);
    const float* xp = x + j0*288 + lane;
    if (FIRST){
      xjn0 = xp[0];
    } else {
      #pragma unroll
      for (int b=0;b<9;b++) xjn[b] = xp[b*32];
    }
  }

  #pragma unroll
  for (int k=0;k<CHUNK;k++){
    int e = base + k;
    if (e >= n_edges) break;           // uniform within the group

    float xj[9]; float xj0;
    if (FIRST){
      xj0 = xjn0;
    } else {
      #pragma unroll
      for (int b=0;b<9;b++) xj[b] = xjn[b];
    }

    // prefetch next edge's xj while computing this one
    if (k+1 < CHUNK){
      int jn = __shfl(pidx, 16+k+1, 32);
      const float* xp = x + jn*288 + lane;
      if (FIRST){
        xjn0 = xp[0];
      } else {
        #pragma unroll
        for (int b=0;b<9;b++) xjn[b] = xp[b*32];
      }
    }

    int ii = __shfl(pidx, k, 32);

    // r_ij components from the preloaded chunk (compile-time lane indices)
    float rx = (3*k+0 < 32) ? __shfl(rv0, 3*k+0, 32) : __shfl(rv1, 3*k+0-32, 32);
    float ry = (3*k+1 < 32) ? __shfl(rv0, 3*k+1, 32) : __shfl(rv1, 3*k+1-32, 32);
    float rz = (3*k+2 < 32) ? __shfl(rv0, 3*k+2, 32) : __shfl(rv1, 3*k+2-32, 32);

    float d2 = fmaf(rx,rx,fmaf(ry,ry,rz*rz));
    float dd = sqrtf(d2);
    float inv = __fdividef(1.0f, dd);
    float X = rx*inv, Yv = ry*inv, Zv = rz*inv;
    const float c1 = 0.4886025119029199f, c2 = 1.0925484305920792f;
    float Y[9];
    Y[0]=0.28209479177387814f; Y[1]=c1*Yv; Y[2]=c1*Zv; Y[3]=c1*X;
    Y[4]=c2*X*Yv; Y[5]=c2*Yv*Zv; Y[6]=0.31539156525252005f*(3.f*Zv*Zv-1.f);
    Y[7]=c2*X*Zv; Y[8]=0.5462742152960396f*(X*X-Yv*Yv);

    // RBF: lane r computes its own basis value, broadcast via shuffle
    float dtl = dd - myoff;
    float rbl = __expf(ALPHA*dtl*dtl);
    float wl0=bfl[0], wl1=bfl[1], wl2=bfl[2];
    #pragma unroll
    for (int r=0;r<20;r++){
      float rb = __shfl(rbl, r, 32);
      wl0 = fmaf(rb, wfr[0][r], wl0);
      wl1 = fmaf(rb, wfr[1][r], wl1);
      wl2 = fmaf(rb, wfr[2][r], wl2);
    }
    float fc = (dd < 5.0f) ? 0.5f*(__cosf(dd*0.6283185307179586f)+1.0f) : 0.0f;
    wl0*=fc; wl1*=fc; wl2*=fc;

    if (ii != cur_i){
      if (cur_i >= 0){
        float* dp = dx + cur_i*288 + lane;
        #pragma unroll
        for (int c=0;c<9;c++){ atomicAdd(dp + c*32, racc[c]); racc[c]=0.f; }
      }
      cur_i = ii;
    }

    if (FIRST){
      // yv[c] = Y[c]*xj0 exactly (CG[a][0][c] = delta_ac)
      racc[0] = fmaf(wl0, Y[0]*xj0, racc[0]);
      #pragma unroll
      for (int c=1;c<4;c++) racc[c] = fmaf(wl1, Y[c]*xj0, racc[c]);
      #pragma unroll
      for (int c=4;c<9;c++) racc[c] = fmaf(wl2, Y[c]*xj0, racc[c]);
    } else {
      // yv[c] = sum_{a,b} Y[a] * CG[a][b][c] * xj[b]  (compile-time sparse)
      float yv[9];
      #pragma unroll
      for (int c=0;c<9;c++) yv[c]=0.f;
      #pragma unroll
      for (int a=0;a<9;a++){
        #pragma unroll
        for (int b=0;b<9;b++){
          bool any = false;
          #pragma unroll
          for (int c=0;c<9;c++) any = any | (CGT.v[a][b][c] != 0.f);
          if (any){
            float p = Y[a]*xj[b];
            #pragma unroll
            for (int c=0;c<9;c++){
              if (CGT.v[a][b][c] != 0.f) yv[c] = fmaf(CGT.v[a][b][c], p, yv[c]);
            }
          }
        }
      }
      racc[0] = fmaf(wl0, yv[0], racc[0]);
      #pragma unroll
      for (int c=1;c<4;c++) racc[c] = fmaf(wl1, yv[c], racc[c]);
      #pragma unroll
      for (int c=4;c<9;c++) racc[c] = fmaf(wl2, yv[c], racc[c]);
    }
  }
  if (cur_i >= 0){
    float* dp = dx + cur_i*288 + lane;
    #pragma unroll
    for (int c=0;c<9;c++) atomicAdd(dp + c*32, racc[c]);
  }
}

// ---------------- atom kernel ----------------
// One atom per 32-lane group, 8 per block, 2500 blocks. No LDS weight
// staging: out[c][k] = sum_n t[c][n]*W[k][n] means lane k wants ROW k of W,
// contiguous in global — load float4 rows straight from the L1/L2-hot 4 KB
// tables. LDS = per-group tile only; no __syncthreads (same-wave ordering).
__global__ __launch_bounds__(256) void atom_kernel(
    float* __restrict__ x, float* __restrict__ dxg,
    const float* __restrict__ Wm1_t, const float* __restrict__ Wm2_t, const float* __restrict__ Wm3_t,
    const float* __restrict__ Wg_t, const float* __restrict__ bg_t, int n_atoms)
{
  __shared__ __align__(16) float tile[8][288];
  int tid = threadIdx.x;
  int g = tid>>5, k = tid&31;
  int atom = blockIdx.x*8 + g;
  if (atom >= n_atoms) return;
  float* tg = &tile[g][0];
  const float4* t4 = reinterpret_cast<const float4*>(tg);

  float* dp = dxg + atom*288 + k;
  float v[9];
  #pragma unroll
  for (int c=0;c<9;c++){ v[c]=dp[c*32]; tg[c*32+k]=v[c]; dp[c*32]=0.f; }  // consume + re-zero

  // ddx = dx @ Wm1^T   (lane k = output channel; row k of Wm1 is contiguous)
  float wr[32];
  {
    const float4* w4 = reinterpret_cast<const float4*>(Wm1_t + k*32);
    #pragma unroll
    for (int q=0;q<8;q++){ float4 a=w4[q]; wr[4*q]=a.x; wr[4*q+1]=a.y; wr[4*q+2]=a.z; wr[4*q+3]=a.w; }
  }
  float u[9];
  #pragma unroll
  for (int c=0;c<9;c++){
    float s=0.f;
    #pragma unroll
    for (int q=0;q<8;q++){
      float4 tv = t4[c*8+q];
      s = fmaf(tv.x, wr[4*q+0], s); s = fmaf(tv.y, wr[4*q+1], s);
      s = fmaf(tv.z, wr[4*q+2], s); s = fmaf(tv.w, wr[4*q+3], s);
    }
    u[c]=s;
  }

  // w[c] = v[c] + sum_{a,b} CG[a][b][c] v[a] u[b]  (compile-time sparse)
  float w[9];
  #pragma unroll
  for (int c=0;c<9;c++) w[c]=v[c];
  #pragma unroll
  for (int a=0;a<9;a++){
    #pragma unroll
    for (int b=0;b<9;b++){
      bool any = false;
      #pragma unroll
      for (int c=0;c<9;c++) any = any | (CGT.v[a][b][c] != 0.f);
      if (any){
        float p = v[a]*u[b];
        #pragma unroll
        for (int c=0;c<9;c++){
          if (CGT.v[a][b][c] != 0.f) w[c] = fmaf(CGT.v[a][b][c], p, w[c]);
        }
      }
    }
  }

  // p = w @ Wm2^T
  #pragma unroll
  for (int c=0;c<9;c++) tg[c*32+k]=w[c];
  {
    const float4* w4 = reinterpret_cast<const float4*>(Wm2_t + k*32);
    #pragma unroll
    for (int q=0;q<8;q++){ float4 a=w4[q]; wr[4*q]=a.x; wr[4*q+1]=a.y; wr[4*q+2]=a.z; wr[4*q+3]=a.w; }
  }
  float p[9];
  #pragma unroll
  for (int c=0;c<9;c++){
    float s=0.f;
    #pragma unroll
    for (int q=0;q<8;q++){
      float4 tv = t4[c*8+q];
      s = fmaf(tv.x, wr[4*q+0], s); s = fmaf(tv.y, wr[4*q+1], s);
      s = fmaf(tv.z, wr[4*q+2], s); s = fmaf(tv.w, wr[4*q+3], s);
    }
    p[c]=s;
  }

  // gate from p[0,:]: lane k needs rows k, 32+k, 64+k of Wg (contiguous)
  tg[k] = p[0];
  float s0=bg_t[k], s1=bg_t[32+k], s2=bg_t[64+k];
  {
    const float4* wg0 = reinterpret_cast<const float4*>(Wg_t + (     k)*32);
    const float4* wg1 = reinterpret_cast<const float4*>(Wg_t + (32 + k)*32);
    const float4* wg2 = reinterpret_cast<const float4*>(Wg_t + (64 + k)*32);
    #pragma unroll
    for (int q=0;q<8;q++){
      float4 tv = t4[q];
      float4 a0 = wg0[q], a1 = wg1[q], a2 = wg2[q];
      s0 = fmaf(tv.x,a0.x,s0); s0 = fmaf(tv.y,a0.y,s0); s0 = fmaf(tv.z,a0.z,s0); s0 = fmaf(tv.w,a0.w,s0);
      s1 = fmaf(tv.x,a1.x,s1); s1 = fmaf(tv.y,a1.y,s1); s1 = fmaf(tv.z,a1.z,s1); s1 = fmaf(tv.w,a1.w,s1);
      s2 = fmaf(tv.x,a2.x,s2); s2 = fmaf(tv.y,a2.y,s2); s2 = fmaf(tv.z,a2.z,s2); s2 = fmaf(tv.w,a2.w,s2);
    }
  }
  float h0 = 1.f/(1.f+__expf(-s0));
  float h1 = 1.f/(1.f+__expf(-s1));
  float h2 = 1.f/(1.f+__expf(-s2));

  float q9[9];
  q9[0]=p[0]*h0;
  #pragma unroll
  for (int c=1;c<4;c++) q9[c]=p[c]*h1;
  #pragma unroll
  for (int c=4;c<9;c++) q9[c]=p[c]*h2;

  // r = q @ Wm3^T ; x += r
  #pragma unroll
  for (int c=0;c<9;c++) tg[c*32+k]=q9[c];
  {
    const float4* w4 = reinterpret_cast<const float4*>(Wm3_t + k*32);
    #pragma unroll
    for (int q=0;q<8;q++){ float4 a=w4[q]; wr[4*q]=a.x; wr[4*q+1]=a.y; wr[4*q+2]=a.z; wr[4*q+3]=a.w; }
  }
  float* xo = x + atom*288 + k;
  #pragma unroll
  for (int c=0;c<9;c++){
    float s=0.f;
    #pragma unroll
    for (int q=0;q<8;q++){
      float4 tv = t4[c*8+q];
      s = fmaf(tv.x, wr[4*q+0], s); s = fmaf(tv.y, wr[4*q+1], s);
      s = fmaf(tv.z, wr[4*q+2], s); s = fmaf(tv.w, wr[4*q+3], s);
    }
    xo[c*32] += s;
  }
}

// ---------------- launch ----------------
extern "C" void kernel_launch(void* const* d_in, const int* in_sizes, int n_in,
                              void* d_out, int out_size, void* d_ws, size_t ws_size,
                              hipStream_t stream)
{
  const int*   Z    = (const int*)d_in[0];
  const float* r_ij = (const float*)d_in[1];
  const int*   idxi = (const int*)d_in[2];
  const int*   idxj = (const int*)d_in[3];
  const float* emb  = (const float*)d_in[4];
  const float* Wf   = (const float*)d_in[5];
  const float* bf   = (const float*)d_in[6];
  const float* Wm1  = (const float*)d_in[7];
  const float* Wm2  = (const float*)d_in[8];
  const float* Wm3  = (const float*)d_in[9];
  const float* Wg   = (const float*)d_in[10];
  const float* bg   = (const float*)d_in[11];
  int n_atoms = in_sizes[0];
  int n_edges = in_sizes[1]/3;

  float* x  = (float*)d_out;
  float* dx = (float*)d_ws;

  init_x_kernel<<<(n_atoms*72+255)/256,256,0,stream>>>(Z, emb, (float4*)x, (float4*)dx, n_atoms);

  int eblocks = (n_edges + 8*CHUNK - 1)/(8*CHUNK);
  int ablocks = (n_atoms + 7)/8;

  // t = 0 (x sparse: only l=0 row nonzero)
  edge_kernel<true><<<eblocks,256,0,stream>>>(r_ij, idxi, idxj, x, Wf, bf, dx, n_edges);
  atom_kernel<<<ablocks,256,0,stream>>>(x, dx, Wm1, Wm2, Wm3, Wg, bg, n_atoms);

  // t = 1 (dense)
  edge_kernel<false><<<eblocks,256,0,stream>>>(r_ij, idxi, idxj, x,
                                        Wf + 96*20, bf + 96, dx, n_edges);
  atom_kernel<<<ablocks,256,0,stream>>>(x, dx,
                                        Wm1 + 1024, Wm2 + 1024, Wm3 + 1024,
                                        Wg + 96*32, bg + 96, n_atoms);
}